// Round 16
// baseline (261.009 us; speedup 1.0000x reference)
//
#include <hip/hip_runtime.h>
#include <cstdint>
#include <cstddef>

using short8 = __attribute__((ext_vector_type(8))) short;
using f32x4  = __attribute__((ext_vector_type(4))) float;

constexpr int T_ = 1024;
constexpr int N_ = 1024;
constexpr int M_ = 1023;
constexpr int B_ = 4;
constexpr int E_ = 1024;
constexpr int H_ = 16;
constexpr int D_ = 64;

#define MFMA16(a, b, c) __builtin_amdgcn_mfma_f32_16x16x32_bf16((a), (b), (c), 0, 0, 0)

__device__ __forceinline__ unsigned short f2bf(float f) {
    unsigned int u = __float_as_uint(f);
    u += 0x7FFF + ((u >> 16) & 1);          // round-to-nearest-even
    return (unsigned short)(u >> 16);
}
__device__ __forceinline__ float bf2f(unsigned short s) {
    return __uint_as_float(((unsigned int)s) << 16);
}

// HW packed fp32->bf16 pair conversion (RNE). lo -> bits[15:0], hi -> [31:16].
__device__ __forceinline__ unsigned int cvt_pk_bf16(float lo, float hi) {
    unsigned int r;
    asm("v_cvt_pk_bf16_f32 %0, %1, %2" : "=v"(r) : "v"(lo), "v"(hi));
    return r;
}

// global -> LDS direct copy, 16 B per lane.
typedef __attribute__((address_space(1))) const unsigned char gc_byte;
typedef __attribute__((address_space(3))) unsigned char lds_byte;
__device__ __forceinline__ void gload16(const void* g, void* lds) {
    __builtin_amdgcn_global_load_lds((gc_byte*)(uintptr_t)g,
                                     (lds_byte*)(unsigned int)(uintptr_t)lds,
                                     16, 0, 0);
}

// ---------------------------------------------------------------------------
// Fused conversions + dw gate, one dispatch.
// [0,4096): query->xq | [4096,8192): key->xk | [8192,12288): node_key->xn
// | [12288,15360): ipw->wbf | [15360,16384): out_w hi/lo | [16384,20476):
// dw gate row r = blk-16384.
// ---------------------------------------------------------------------------
__device__ __forceinline__ void conv_body(const float* __restrict__ src,
                                          unsigned short* __restrict__ dst,
                                          int i, int n)
{
    if (i + 4 <= n) {
        const float4 v = *reinterpret_cast<const float4*>(src + i);
        ushort4 o;
        o.x = f2bf(v.x); o.y = f2bf(v.y); o.z = f2bf(v.z); o.w = f2bf(v.w);
        *reinterpret_cast<ushort4*>(dst + i) = o;
    } else {
        for (int k = 0; k < 4; ++k)
            dst[i + k] = (i + k < n) ? f2bf(src[i + k]) : (unsigned short)0;
    }
}

__global__ void conv_all(const float* __restrict__ query,
                         const float* __restrict__ key,
                         const float* __restrict__ node_key,
                         const float* __restrict__ ipw,
                         const float* __restrict__ out_w,
                         const float* __restrict__ dw_w,
                         const float* __restrict__ dw_b,
                         unsigned short* __restrict__ xq,
                         unsigned short* __restrict__ xk,
                         unsigned short* __restrict__ xn,
                         unsigned short* __restrict__ wbf,
                         unsigned short* __restrict__ wohi,
                         unsigned short* __restrict__ wolo,
                         float* __restrict__ dwb)
{
    __shared__ float rowbuf[E_];
    const int blk = blockIdx.x;
    const int tid = threadIdx.x;
    if (blk < 4096) {
        conv_body(query, xq, (blk * 256 + tid) * 4, 4194304);
    } else if (blk < 8192) {
        conv_body(key, xk, ((blk - 4096) * 256 + tid) * 4, 4194304);
    } else if (blk < 12288) {
        conv_body(node_key, xn, ((blk - 8192) * 256 + tid) * 4, 4190208);
    } else if (blk < 15360) {
        conv_body(ipw, wbf, ((blk - 12288) * 256 + tid) * 4, 3145728);
    } else if (blk < 16384) {
        const int i = ((blk - 15360) * 256 + tid) * 4;
        const float4 v = *reinterpret_cast<const float4*>(out_w + i);
        float a[4] = {v.x, v.y, v.z, v.w};
        ushort4 hi, lo;
        unsigned short h[4], l[4];
        #pragma unroll
        for (int k = 0; k < 4; ++k) {
            h[k] = f2bf(a[k]);
            l[k] = f2bf(a[k] - bf2f(h[k]));
        }
        hi.x = h[0]; hi.y = h[1]; hi.z = h[2]; hi.w = h[3];
        lo.x = l[0]; lo.y = l[1]; lo.z = l[2]; lo.w = l[3];
        *reinterpret_cast<ushort4*>(wohi + i) = hi;
        *reinterpret_cast<ushort4*>(wolo + i) = lo;
    } else {
        // dw gate: r = blk - 16384  (r < M_*B_ = 4092)
        const int r = blk - 16384;
        for (int idx = tid; idx < E_; idx += 256)
            rowbuf[idx] = node_key[(size_t)r * E_ + idx];
        __syncthreads();
        const int h = tid >> 4;
        const int lane = tid & 15;
        float acc = 0.f;
        const float* wrow = dw_w + (size_t)h * E_;
        for (int k = lane; k < E_; k += 16)
            acc = fmaf(rowbuf[k], wrow[k], acc);
        acc += __shfl_xor(acc, 8);
        acc += __shfl_xor(acc, 4);
        acc += __shfl_xor(acc, 2);
        acc += __shfl_xor(acc, 1);
        if (lane == 0) {
            float x = acc + dw_b[h];
            dwb[(size_t)r * H_ + h] = 1.f / (1.f + __expf(-x));
        }
    }
}

// ---------------------------------------------------------------------------
// Fused input projections, R16: A DIRECT FROM GLOBAL with DEPTH-2 REGISTER
// PREFETCH (fixes R14: av(t+1) issued right after iter-t's barrier, a full
// iteration of MFMA+W-reads covers the L2 latency). W-only LDS (3 x 8 KB),
// counted vmcnt: steady queue = av(t)[4] + STAGE(t+1)[2] -> vmcnt(2) drains
// av(t) and W(t) (older). A reads are 64B-coalesced (4 lanes cover a row
// line); waves 0/1 share rows via L1. WAR on buf(t+2) fenced by top barrier.
// ---------------------------------------------------------------------------
__global__ __launch_bounds__(256) void proj_mfma(
    const unsigned short* __restrict__ xq,
    const unsigned short* __restrict__ xk,
    const unsigned short* __restrict__ xn,
    const unsigned short* __restrict__ wbf,
    const float* __restrict__ ipb,
    const float* __restrict__ dwb,
    unsigned short* __restrict__ qb,
    unsigned short* __restrict__ kb,
    unsigned short* __restrict__ vtb,
    unsigned short* __restrict__ nkb,
    unsigned short* __restrict__ nvtb)
{
    __shared__ unsigned short LDS[3][4096];   // W tiles only: 3 x 8 KB

    const unsigned short* A;
    const unsigned short* W;
    const float* bias;
    const float* dwm = nullptr;
    unsigned short* out;
    int epi;
    float scale = 1.f;
    switch (blockIdx.z) {
      case 0:  A = xq; W = wbf;           bias = ipb;        out = qb;   epi = 1; scale = 0.18033688011112042f; break;
      case 1:  A = xk; W = wbf + 1048576; bias = ipb + 1024; out = kb;   epi = 1; break;
      case 2:  A = xk; W = wbf + 2097152; bias = ipb + 2048; out = vtb;  epi = 2; break;
      case 3:  A = xn; W = wbf + 1048576; bias = ipb + 1024; out = nkb;  epi = 1; break;
      default: A = xn; W = wbf + 2097152; bias = ipb + 2048; out = nvtb; epi = 2; dwm = dwb; break;
    }

    const int tid = threadIdx.x;
    const int l = tid & 63, w = tid >> 6;
    const int brow = blockIdx.y * 128;
    const int bcol = blockIdx.x * 128;

    // W staging (T2 source swizzle), 2 chunks per thread per stage
    const int ch0 = w * 64 + l;
    const int ch1 = 256 + w * 64 + l;
    const int u0 = ((ch0 & 3) ^ ((ch0 >> 3) & 3)) * 8;
    const int u1 = ((ch1 & 3) ^ ((ch1 >> 3) & 3)) * 8;
    const unsigned short* gW0 = W + (size_t)(bcol + (ch0 >> 2)) * E_ + u0;
    const unsigned short* gW1 = W + (size_t)(bcol + (ch1 >> 2)) * E_ + u1;

    auto STAGE = [&](int buf, int kt) {
        gload16(gW0 + kt, &LDS[buf][(size_t)w * 512]);
        gload16(gW1 + kt, &LDS[buf][(size_t)(4 + w) * 512]);
    };

    f32x4 acc[4][4];
    #pragma unroll
    for (int m = 0; m < 4; ++m)
        #pragma unroll
        for (int n = 0; n < 4; ++n)
            acc[m][n] = (f32x4){0.f, 0.f, 0.f, 0.f};

    const int wr = (w >> 1) * 64, wc = (w & 1) * 64;
    const int fr = l & 15;
    const int ko = (((l >> 4) ^ ((fr >> 1) & 3))) * 8;   // swizzled W read unit

    // A base: lane l -> row (brow + wr + fr [+ m*16]), k-chunk (l>>4)*8
    const unsigned short* gA = A + (size_t)(brow + wr + fr) * E_ + (l >> 4) * 8;

    short8 avA[4], avB[4];

    // prologue: avA(t=0) first, then 2 W-stages; vmcnt(2) drains avA + W0
    #pragma unroll
    for (int m = 0; m < 4; ++m)
        avA[m] = *reinterpret_cast<const short8*>(gA + (size_t)m * 16 * E_);
    STAGE(0, 0);
    STAGE(1, 32);
    asm volatile("s_waitcnt vmcnt(2)" ::: "memory");

#define PROJ_STEP(T, CUR, NXT)                                                  \
    {                                                                           \
        const int t_ = (T);                                                     \
        if (t_ > 0) {                                                           \
            if (t_ < 31) asm volatile("s_waitcnt vmcnt(2)" ::: "memory");       \
            else         asm volatile("s_waitcnt vmcnt(0)" ::: "memory");       \
        }                                                                       \
        __builtin_amdgcn_sched_barrier(0);                                      \
        __builtin_amdgcn_s_barrier();                                           \
        __builtin_amdgcn_sched_barrier(0);                                      \
        if (t_ < 31) {                                                          \
            _Pragma("unroll")                                                   \
            for (int m = 0; m < 4; ++m)                                         \
                NXT[m] = *reinterpret_cast<const short8*>(                      \
                    gA + (size_t)m * 16 * E_ + (t_ + 1) * 32);                  \
        }                                                                       \
        if (t_ < 30) STAGE((t_ + 2) % 3, (t_ + 2) * 32);                        \
        __builtin_amdgcn_sched_barrier(0);                                      \
        const int cur_ = t_ % 3;                                                \
        short8 bv[4];                                                           \
        _Pragma("unroll")                                                       \
        for (int n = 0; n < 4; ++n)                                             \
            bv[n] = *reinterpret_cast<const short8*>(                           \
                &LDS[cur_][(wc + n * 16 + fr) * 32 + ko]);                      \
        __builtin_amdgcn_s_setprio(1);                                          \
        _Pragma("unroll")                                                       \
        for (int m = 0; m < 4; ++m)                                             \
            _Pragma("unroll")                                                   \
            for (int n = 0; n < 4; ++n)                                         \
                acc[m][n] = MFMA16(CUR[m], bv[n], acc[m][n]);                   \
        __builtin_amdgcn_s_setprio(0);                                          \
    }

    for (int tt = 0; tt < 32; tt += 2) {
        PROJ_STEP(tt,     avA, avB);
        PROJ_STEP(tt + 1, avB, avA);
    }
#undef PROJ_STEP

    #pragma unroll
    for (int n = 0; n < 4; ++n) {
        const int c = bcol + wc + n * 16 + fr;
        const float bi = bias[c];
        #pragma unroll
        for (int m = 0; m < 4; ++m) {
            #pragma unroll
            for (int j = 0; j < 4; ++j) {
                const int r = brow + wr + m * 16 + (l >> 4) * 4 + j;
                float v = (acc[m][n][j] + bi) * scale;
                const int rn = r >> 2, b = r & 3, hh = c >> 6, dd = c & 63;
                if (epi == 1) {
                    out[((size_t)(b * H_ + hh) * 1024 + rn) * 64 + dd] = f2bf(v);
                } else {
                    if (dwm) v *= dwm[(size_t)r * H_ + hh];
                    out[(((size_t)(b * H_ + hh) * 32 + (rn >> 5)) * 64 + dd) * 32 + (rn & 31)] = f2bf(v);
                }
            }
        }
    }
}

// ---------------------------------------------------------------------------
// Output projection, 2-term (R13): out = ohi . (whi + wlo)^T + b.
// ---------------------------------------------------------------------------
__global__ __launch_bounds__(256) void outproj_mfma(
    const unsigned short* __restrict__ ahi,
    const unsigned short* __restrict__ whi,
    const unsigned short* __restrict__ wlo,
    const float* __restrict__ out_b,
    float* __restrict__ out)
{
    __shared__ unsigned short LDS[2][3][128 * 32];   // 48 KB

    const int tid = threadIdx.x;
    const int l = tid & 63, w = tid >> 6;
    const int brow = blockIdx.y * 128;
    const int bcol = blockIdx.x * 128;

    const int ch0 = w * 64 + l;
    const int ch1 = 256 + w * 64 + l;
    const int u0 = ((ch0 & 3) ^ ((ch0 >> 3) & 3)) * 8;
    const int u1 = ((ch1 & 3) ^ ((ch1 >> 3) & 3)) * 8;
    const size_t ra0 = (size_t)(brow + (ch0 >> 2)) * E_ + u0;
    const size_t ra1 = (size_t)(brow + (ch1 >> 2)) * E_ + u1;
    const size_t rb0 = (size_t)(bcol + (ch0 >> 2)) * E_ + u0;
    const size_t rb1 = (size_t)(bcol + (ch1 >> 2)) * E_ + u1;

    auto STAGE = [&](int buf, int kt) {
        gload16(ahi + ra0 + kt, &LDS[buf][0][(size_t)w * 512]);
        gload16(ahi + ra1 + kt, &LDS[buf][0][(size_t)(4 + w) * 512]);
        gload16(whi + rb0 + kt, &LDS[buf][1][(size_t)w * 512]);
        gload16(whi + rb1 + kt, &LDS[buf][1][(size_t)(4 + w) * 512]);
        gload16(wlo + rb0 + kt, &LDS[buf][2][(size_t)w * 512]);
        gload16(wlo + rb1 + kt, &LDS[buf][2][(size_t)(4 + w) * 512]);
    };

    f32x4 acc[4][4];
    #pragma unroll
    for (int m = 0; m < 4; ++m)
        #pragma unroll
        for (int n = 0; n < 4; ++n)
            acc[m][n] = (f32x4){0.f, 0.f, 0.f, 0.f};

    const int wr = (w >> 1) * 64, wc = (w & 1) * 64;
    const int fr = l & 15;
    const int ko = (((l >> 4) ^ ((fr >> 1) & 3))) * 8;   // swizzled read unit

    STAGE(0, 0);
    __syncthreads();
    for (int t = 0; t < 32; ++t) {
        const int cur = t & 1;
        if (t < 31) STAGE(cur ^ 1, (t + 1) * 32);
        short8 ah[4], bh[4], bl[4];
        #pragma unroll
        for (int m = 0; m < 4; ++m)
            ah[m] = *reinterpret_cast<const short8*>(&LDS[cur][0][(wr + m * 16 + fr) * 32 + ko]);
        #pragma unroll
        for (int n = 0; n < 4; ++n) {
            bh[n] = *reinterpret_cast<const short8*>(&LDS[cur][1][(wc + n * 16 + fr) * 32 + ko]);
            bl[n] = *reinterpret_cast<const short8*>(&LDS[cur][2][(wc + n * 16 + fr) * 32 + ko]);
        }
        __builtin_amdgcn_s_setprio(1);
        #pragma unroll
        for (int m = 0; m < 4; ++m)
            #pragma unroll
            for (int n = 0; n < 4; ++n) {
                acc[m][n] = MFMA16(ah[m], bh[n], acc[m][n]);
                acc[m][n] = MFMA16(ah[m], bl[n], acc[m][n]);
            }
        __builtin_amdgcn_s_setprio(0);
        if (t < 31) __syncthreads();
    }

    #pragma unroll
    for (int n = 0; n < 4; ++n) {
        const int c = bcol + wc + n * 16 + fr;
        const float bi = out_b[c];
        #pragma unroll
        for (int m = 0; m < 4; ++m)
            #pragma unroll
            for (int j = 0; j < 4; ++j) {
                const int r = brow + wr + m * 16 + (l >> 4) * 4 + j;
                out[(size_t)r * E_ + c] = acc[m][n][j] + bi;
            }
    }
}

// ---------------------------------------------------------------------------
// MFMA flash attention, full-S (R15 structure, unchanged).
// ---------------------------------------------------------------------------
__global__ __launch_bounds__(256) void attn_mfma(
    const unsigned short* __restrict__ qbf,
    const unsigned short* __restrict__ kbf,
    const unsigned short* __restrict__ nkbf,
    const unsigned short* __restrict__ vtb,
    const unsigned short* __restrict__ nvtb,
    const unsigned char* __restrict__ kpm,
    const unsigned char* __restrict__ npm,
    unsigned short* __restrict__ ohi)
{
    __shared__ unsigned short Kl[2][64 * 64];   // 8 KB each, swizzled rows
    __shared__ unsigned short Vl[2][64 * 64];   // 8 KB each, [kg][d][k8]
    __shared__ unsigned short maskB[2048];      // bf16 additive mask (4 KB)
    __shared__ int tmask[32];

    const int tid = threadIdx.x;
    const int l = tid & 63, w = tid >> 6;
    const int bh = blockIdx.x, b = bh >> 4, h = bh & 15;
    const int t0 = blockIdx.y * 64;

    if (tid < 32) tmask[tid] = 0;
    __syncthreads();
    {
        const unsigned short negbf = f2bf(-60000.f);
        for (int s = tid; s < 2048; s += 256) {
            int masked;
            if (s < N_) masked = kpm[(size_t)b * N_ + s] ? 1 : 0;
            else {
                const int m = s - N_;
                masked = (m < M_ && !npm[(size_t)b * M_ + m]) ? 0 : 1;
            }
            maskB[s] = masked ? negbf : (unsigned short)0;
            if (masked) atomicOr(&tmask[s >> 6], 1);
        }
    }

    auto STAGE = [&](int buf, int s0) {
        const unsigned short* ksrc;
        const unsigned short* vsrc;
        int srow;
        if (s0 < N_) { ksrc = kbf;  vsrc = vtb;  srow = s0; }
        else         { ksrc = nkbf; vsrc = nvtb; srow = s0 - N_; }
        #pragma unroll
        for (int u = 0; u < 2; ++u) {
            const int c = u * 256 + tid;
            const int krow = c >> 3;
            const int kcol = ((c & 7) * 16) ^ ((krow & 7) << 4);
            gload16((const unsigned char*)ksrc +
                        ((size_t)(bh * 1024 + srow + krow) * 64) * 2 + kcol,
                    (unsigned char*)&Kl[buf][0] + c * 16);
            const int kg = c >> 6;
            const int dd = c & 63;
            const int kv = srow + kg * 8;
            const int kp = kv >> 5;
            gload16((const unsigned char*)vsrc +
                        (((size_t)(bh * 32 + kp) * 64 + dd) * 32 + (kv & 31)) * 2,
                    (unsigned char*)&Vl[buf][0] + c * 16);
        }
    };

    const int g = l >> 4;
    const int q = l & 15;

    const int qrow = t0 + w * 16 + q;
    const short8 aq0 = *reinterpret_cast<const short8*>(&qbf[((size_t)bh * T_ + qrow) * 64 + g * 8]);
    const short8 aq1 = *reinterpret_cast<const short8*>(&qbf[((size_t)bh * T_ + qrow) * 64 + 32 + g * 8]);

    float mold = -30000.f, lrp = 0.f;   // lrp: per-lane PARTIAL row-sum
    f32x4 acco[4];
    #pragma unroll
    for (int n = 0; n < 4; ++n) acco[n] = (f32x4){0.f, 0.f, 0.f, 0.f};

    const int ksw = (l & 7) << 4;
    const int kb0 = q * 128 + ((g * 16) ^ ksw);        // + n*2048
    const int kb1 = q * 128 + ((64 + g * 16) ^ ksw);   // + n*2048
    const int vb0 = g * 1024 + q * 16;                 // + n*256 (+4096 half 1)

    const int src0 = (g & 1) * 32 + q;   // words 0,1
    const int src1 = src0 + 16;          // words 2,3
    const bool selhi = (l & 32) != 0;

    STAGE(0, 0);
    __syncthreads();

    for (int it = 0; it < 32; ++it) {
        const int s0 = it * 64;
        const int cur = it & 1;
        if (it < 31) STAGE(cur ^ 1, s0 + 64);

        const unsigned char* const Kc = (const unsigned char*)&Kl[cur][0];
        const unsigned char* const Vc = (const unsigned char*)&Vl[cur][0];

        f32x4 accs[4];
        #pragma unroll
        for (int n = 0; n < 4; ++n) accs[n] = (f32x4){0.f, 0.f, 0.f, 0.f};
        __builtin_amdgcn_s_setprio(1);
        #pragma unroll
        for (int n = 0; n < 4; ++n) {
            const short8 k0 = *reinterpret_cast<const short8*>(Kc + n * 2048 + kb0);
            const short8 k1 = *reinterpret_cast<const short8*>(Kc + n * 2048 + kb1);
            accs[n] = MFMA16(k0, aq0, accs[n]);
            accs[n] = MFMA16(k1, aq1, accs[n]);
        }
        __builtin_amdgcn_s_setprio(0);

        if (tmask[s0 >> 6]) {
            #pragma unroll
            for (int n = 0; n < 4; ++n) {
                const ushort4 mz = *reinterpret_cast<const ushort4*>(&maskB[s0 + n * 16 + g * 4]);
                accs[n][0] += bf2f(mz.x);
                accs[n][1] += bf2f(mz.y);
                accs[n][2] += bf2f(mz.z);
                accs[n][3] += bf2f(mz.w);
            }
        }

        float mx;
        {
            const float t0_ = fmaxf(fmaxf(accs[0][0], accs[0][1]), accs[0][2]);
            const float t1_ = fmaxf(fmaxf(accs[0][3], accs[1][0]), accs[1][1]);
            const float t2_ = fmaxf(fmaxf(accs[1][2], accs[1][3]), accs[2][0]);
            const float t3_ = fmaxf(fmaxf(accs[2][1], accs[2][2]), accs[2][3]);
            const float t4_ = fmaxf(fmaxf(accs[3][0], accs[3][1]), accs[3][2]);
            const float t5_ = fmaxf(fmaxf(t0_, t1_), t2_);
            const float t6_ = fmaxf(fmaxf(t3_, t4_), accs[3][3]);
            mx = fmaxf(t5_, t6_);
        }
        mx = fmaxf(mx, __shfl_xor(mx, 16));
        mx = fmaxf(mx, __shfl_xor(mx, 32));

        if (__any(mx > mold + 8.f)) {
            const float mn = fmaxf(mold, mx);
            const float f = __builtin_amdgcn_exp2f(mold - mn);
            mold = mn;
            lrp *= f;
            #pragma unroll
            for (int n = 0; n < 4; ++n)
                #pragma unroll
                for (int j = 0; j < 4; ++j) acco[n][j] *= f;
        }

        float p[4][4];
        float ps = 0.f;
        #pragma unroll
        for (int n = 0; n < 4; ++n)
            #pragma unroll
            for (int j = 0; j < 4; ++j) {
                p[n][j] = __builtin_amdgcn_exp2f(accs[n][j] - mold);
                ps += p[n][j];
            }
        lrp += ps;

        unsigned int ppk[4][2];
        #pragma unroll
        for (int n = 0; n < 4; ++n) {
            ppk[n][0] = cvt_pk_bf16(p[n][0], p[n][1]);
            ppk[n][1] = cvt_pk_bf16(p[n][2], p[n][3]);
        }

        union UF { int4 i4; short8 s8; } pf[2];
        #pragma unroll
        for (int hh2 = 0; hh2 < 2; ++hh2) {
            const unsigned int a0 = __shfl((int)ppk[2 * hh2][0],     src0);
            const unsigned int b0 = __shfl((int)ppk[2 * hh2 + 1][0], src0);
            const unsigned int a1 = __shfl((int)ppk[2 * hh2][1],     src0);
            const unsigned int b1 = __shfl((int)ppk[2 * hh2 + 1][1], src0);
            const unsigned int a2 = __shfl((int)ppk[2 * hh2][0],     src1);
            const unsigned int b2 = __shfl((int)ppk[2 * hh2 + 1][0], src1);
            const unsigned int a3 = __shfl((int)ppk[2 * hh2][1],     src1);
            const unsigned int b3 = __shfl((int)ppk[2 * hh2 + 1][1], src1);
            pf[hh2].i4.x = selhi ? b0 : a0;
            pf[hh2].i4.y = selhi ? b1 : a1;
            pf[hh2].i4.z = selhi ? b2 : a2;
            pf[hh2].i4.w = selhi ? b3 : a3;
        }

        __builtin_amdgcn_s_setprio(1);
        #pragma unroll
        for (int n = 0; n < 4; ++n) {
            const short8 v0 = *reinterpret_cast<const short8*>(Vc + n * 256 + vb0);
            const short8 v1 = *reinterpret_cast<const short8*>(Vc + 4096 + n * 256 + vb0);
            acco[n] = MFMA16(v0, pf[0].s8, acco[n]);
            acco[n] = MFMA16(v1, pf[1].s8, acco[n]);
        }
        __builtin_amdgcn_s_setprio(0);

        __syncthreads();
    }

    float lr = lrp;
    lr += __shfl_xor(lr, 16);
    lr += __shfl_xor(lr, 32);
    const float linv = 1.f / lr;
    const int t = t0 + w * 16 + q;
    const size_t obase = ((size_t)t * B_ + b) * E_ + h * 64;
    #pragma unroll
    for (int n = 0; n < 4; ++n) {
        ushort4 h4;
        h4.x = f2bf(acco[n][0] * linv);
        h4.y = f2bf(acco[n][1] * linv);
        h4.z = f2bf(acco[n][2] * linv);
        h4.w = f2bf(acco[n][3] * linv);
        *reinterpret_cast<ushort4*>(&ohi[obase + n * 16 + g * 4]) = h4;
    }
}

// ---------------------------------------------------------------------------
extern "C" void kernel_launch(void* const* d_in, const int* in_sizes, int n_in,
                              void* d_out, int out_size, void* d_ws, size_t ws_size,
                              hipStream_t stream) {
    const float* query    = (const float*)d_in[0];
    const float* key      = (const float*)d_in[1];
    const float* node_key = (const float*)d_in[2];
    const float* ipw      = (const float*)d_in[3];
    const float* ipb      = (const float*)d_in[4];
    const float* out_w    = (const float*)d_in[5];
    const float* out_b    = (const float*)d_in[6];
    const float* dw_w     = (const float*)d_in[7];
    const float* dw_b     = (const float*)d_in[8];
    const unsigned char* kpm = (const unsigned char*)d_in[9];
    const unsigned char* npm = (const unsigned char*)d_in[10];
    float* out = (float*)d_out;

    char* p = (char*)d_ws;
    auto alloc = [&](size_t bytes) {
        char* r = p;
        p += (bytes + 255) & ~(size_t)255;
        return r;
    };
    unsigned short* xq    = (unsigned short*)alloc((size_t)4096 * 1024 * 2);
    unsigned short* xk    = (unsigned short*)alloc((size_t)4096 * 1024 * 2);
    unsigned short* xn    = (unsigned short*)alloc((size_t)4096 * 1024 * 2);
    unsigned short* wbf   = (unsigned short*)alloc((size_t)3072 * 1024 * 2);
    unsigned short* wohi  = (unsigned short*)alloc((size_t)1024 * 1024 * 2);
    unsigned short* wolo  = (unsigned short*)alloc((size_t)1024 * 1024 * 2);
    unsigned short* qb    = (unsigned short*)alloc((size_t)64 * 1024 * 64 * 2);
    unsigned short* kb_   = (unsigned short*)alloc((size_t)64 * 1024 * 64 * 2);
    unsigned short* nkb   = (unsigned short*)alloc((size_t)64 * 1024 * 64 * 2);
    unsigned short* vtb   = (unsigned short*)alloc((size_t)64 * 1024 * 64 * 2);
    unsigned short* nvtb  = (unsigned short*)alloc((size_t)64 * 1024 * 64 * 2);
    unsigned short* ohi   = (unsigned short*)alloc((size_t)4096 * 1024 * 2);
    float*          dwb   = (float*)alloc((size_t)4096 * 16 * 4);

    const dim3 blk(256);

    // 1) all conversions + dw gate in one dispatch
    conv_all<<<dim3(16384 + 4092), blk, 0, stream>>>(
        query, key, node_key, ipw, out_w, dw_w, dw_b,
        xq, xk, xn, wbf, wohi, wolo, dwb);

    // 2) fused input projections (A-direct depth-2 prefetch, W-only LDS)
    proj_mfma<<<dim3(8, 32, 5), blk, 0, stream>>>(xq, xk, xn, wbf, ipb, dwb,
                                                  qb, kb_, vtb, nkb, nvtb);

    // 3) attention, full-S -> ohi (bf16)
    attn_mfma<<<dim3(64, 16), blk, 0, stream>>>(qb, kb_, nkb, vtb, nvtb,
                                                kpm, npm, ohi);

    // 4) output projection (2-term: ohi.(whi+wlo)) -> d_out fp32
    outproj_mfma<<<dim3(8, 32), blk, 0, stream>>>(ohi, wohi, wolo, out_b, out);
}

// Round 17
// 228.573 us; speedup vs baseline: 1.1419x; 1.1419x over previous
//
#include <hip/hip_runtime.h>
#include <cstdint>
#include <cstddef>

using short8 = __attribute__((ext_vector_type(8))) short;
using f32x4  = __attribute__((ext_vector_type(4))) float;

constexpr int T_ = 1024;
constexpr int N_ = 1024;
constexpr int M_ = 1023;
constexpr int B_ = 4;
constexpr int E_ = 1024;
constexpr int H_ = 16;
constexpr int D_ = 64;

#define MFMA16(a, b, c) __builtin_amdgcn_mfma_f32_16x16x32_bf16((a), (b), (c), 0, 0, 0)

__device__ __forceinline__ unsigned short f2bf(float f) {
    unsigned int u = __float_as_uint(f);
    u += 0x7FFF + ((u >> 16) & 1);          // round-to-nearest-even
    return (unsigned short)(u >> 16);
}
__device__ __forceinline__ float bf2f(unsigned short s) {
    return __uint_as_float(((unsigned int)s) << 16);
}

// HW packed fp32->bf16 pair conversion (RNE). lo -> bits[15:0], hi -> [31:16].
__device__ __forceinline__ unsigned int cvt_pk_bf16(float lo, float hi) {
    unsigned int r;
    asm("v_cvt_pk_bf16_f32 %0, %1, %2" : "=v"(r) : "v"(lo), "v"(hi));
    return r;
}

// global -> LDS direct copy, 16 B per lane.
typedef __attribute__((address_space(1))) const unsigned char gc_byte;
typedef __attribute__((address_space(3))) unsigned char lds_byte;
__device__ __forceinline__ void gload16(const void* g, void* lds) {
    __builtin_amdgcn_global_load_lds((gc_byte*)(uintptr_t)g,
                                     (lds_byte*)(unsigned int)(uintptr_t)lds,
                                     16, 0, 0);
}

// ---------------------------------------------------------------------------
// Fused conversions + dw gate, one dispatch (R16 fusion — kept; it banked
// ~6 µs once separated from the proj regression).
// ---------------------------------------------------------------------------
__device__ __forceinline__ void conv_body(const float* __restrict__ src,
                                          unsigned short* __restrict__ dst,
                                          int i, int n)
{
    if (i + 4 <= n) {
        const float4 v = *reinterpret_cast<const float4*>(src + i);
        ushort4 o;
        o.x = f2bf(v.x); o.y = f2bf(v.y); o.z = f2bf(v.z); o.w = f2bf(v.w);
        *reinterpret_cast<ushort4*>(dst + i) = o;
    } else {
        for (int k = 0; k < 4; ++k)
            dst[i + k] = (i + k < n) ? f2bf(src[i + k]) : (unsigned short)0;
    }
}

__global__ void conv_all(const float* __restrict__ query,
                         const float* __restrict__ key,
                         const float* __restrict__ node_key,
                         const float* __restrict__ ipw,
                         const float* __restrict__ out_w,
                         const float* __restrict__ dw_w,
                         const float* __restrict__ dw_b,
                         unsigned short* __restrict__ xq,
                         unsigned short* __restrict__ xk,
                         unsigned short* __restrict__ xn,
                         unsigned short* __restrict__ wbf,
                         unsigned short* __restrict__ wohi,
                         unsigned short* __restrict__ wolo,
                         float* __restrict__ dwb)
{
    __shared__ float rowbuf[E_];
    const int blk = blockIdx.x;
    const int tid = threadIdx.x;
    if (blk < 4096) {
        conv_body(query, xq, (blk * 256 + tid) * 4, 4194304);
    } else if (blk < 8192) {
        conv_body(key, xk, ((blk - 4096) * 256 + tid) * 4, 4194304);
    } else if (blk < 12288) {
        conv_body(node_key, xn, ((blk - 8192) * 256 + tid) * 4, 4190208);
    } else if (blk < 15360) {
        conv_body(ipw, wbf, ((blk - 12288) * 256 + tid) * 4, 3145728);
    } else if (blk < 16384) {
        const int i = ((blk - 15360) * 256 + tid) * 4;
        const float4 v = *reinterpret_cast<const float4*>(out_w + i);
        float a[4] = {v.x, v.y, v.z, v.w};
        ushort4 hi, lo;
        unsigned short h[4], l[4];
        #pragma unroll
        for (int k = 0; k < 4; ++k) {
            h[k] = f2bf(a[k]);
            l[k] = f2bf(a[k] - bf2f(h[k]));
        }
        hi.x = h[0]; hi.y = h[1]; hi.z = h[2]; hi.w = h[3];
        lo.x = l[0]; lo.y = l[1]; lo.z = l[2]; lo.w = l[3];
        *reinterpret_cast<ushort4*>(wohi + i) = hi;
        *reinterpret_cast<ushort4*>(wolo + i) = lo;
    } else {
        // dw gate: r = blk - 16384  (r < M_*B_ = 4092)
        const int r = blk - 16384;
        for (int idx = tid; idx < E_; idx += 256)
            rowbuf[idx] = node_key[(size_t)r * E_ + idx];
        __syncthreads();
        const int h = tid >> 4;
        const int lane = tid & 15;
        float acc = 0.f;
        const float* wrow = dw_w + (size_t)h * E_;
        for (int k = lane; k < E_; k += 16)
            acc = fmaf(rowbuf[k], wrow[k], acc);
        acc += __shfl_xor(acc, 8);
        acc += __shfl_xor(acc, 4);
        acc += __shfl_xor(acc, 2);
        acc += __shfl_xor(acc, 1);
        if (lane == 0) {
            float x = acc + dw_b[h];
            dwb[(size_t)r * H_ + h] = 1.f / (1.f + __expf(-x));
        }
    }
}

// ---------------------------------------------------------------------------
// Fused input projections — R13/R10 proven best (128x128, LDS A+W, 3-buffer
// counted-vmcnt, T2 swizzle). A-direct-from-L2 refuted twice (R14, R16:
// per-lane flat loads saturate the L2 request path; gload_lds amortizes
// 1 req / 16 lanes). Do not touch the staging structure again.
// ---------------------------------------------------------------------------
__global__ __launch_bounds__(256) void proj_mfma(
    const unsigned short* __restrict__ xq,
    const unsigned short* __restrict__ xk,
    const unsigned short* __restrict__ xn,
    const unsigned short* __restrict__ wbf,
    const float* __restrict__ ipb,
    const float* __restrict__ dwb,
    unsigned short* __restrict__ qb,
    unsigned short* __restrict__ kb,
    unsigned short* __restrict__ vtb,
    unsigned short* __restrict__ nkb,
    unsigned short* __restrict__ nvtb)
{
    __shared__ unsigned short LDS[3][2][128 * 32];   // 48 KB, triple-buffered

    const unsigned short* A;
    const unsigned short* W;
    const float* bias;
    const float* dwm = nullptr;
    unsigned short* out;
    int epi;
    float scale = 1.f;
    switch (blockIdx.z) {
      case 0:  A = xq; W = wbf;           bias = ipb;        out = qb;   epi = 1; scale = 0.18033688011112042f; break;
      case 1:  A = xk; W = wbf + 1048576; bias = ipb + 1024; out = kb;   epi = 1; break;
      case 2:  A = xk; W = wbf + 2097152; bias = ipb + 2048; out = vtb;  epi = 2; break;
      case 3:  A = xn; W = wbf + 1048576; bias = ipb + 1024; out = nkb;  epi = 1; break;
      default: A = xn; W = wbf + 2097152; bias = ipb + 2048; out = nvtb; epi = 2; dwm = dwb; break;
    }

    const int tid = threadIdx.x;
    const int l = tid & 63, w = tid >> 6;
    const int brow = blockIdx.y * 128;
    const int bcol = blockIdx.x * 128;

    const int ch0 = w * 64 + l;
    const int ch1 = 256 + w * 64 + l;
    const int u0 = ((ch0 & 3) ^ ((ch0 >> 3) & 3)) * 8;
    const int u1 = ((ch1 & 3) ^ ((ch1 >> 3) & 3)) * 8;
    const unsigned short* gA0 = A + (size_t)(brow + (ch0 >> 2)) * E_ + u0;
    const unsigned short* gA1 = A + (size_t)(brow + (ch1 >> 2)) * E_ + u1;
    const unsigned short* gW0 = W + (size_t)(bcol + (ch0 >> 2)) * E_ + u0;
    const unsigned short* gW1 = W + (size_t)(bcol + (ch1 >> 2)) * E_ + u1;

    auto STAGE = [&](int buf, int kt) {
        gload16(gA0 + kt, &LDS[buf][0][(size_t)w * 512]);
        gload16(gA1 + kt, &LDS[buf][0][(size_t)(4 + w) * 512]);
        gload16(gW0 + kt, &LDS[buf][1][(size_t)w * 512]);
        gload16(gW1 + kt, &LDS[buf][1][(size_t)(4 + w) * 512]);
    };

    f32x4 acc[4][4];
    #pragma unroll
    for (int m = 0; m < 4; ++m)
        #pragma unroll
        for (int n = 0; n < 4; ++n)
            acc[m][n] = (f32x4){0.f, 0.f, 0.f, 0.f};

    const int wr = (w >> 1) * 64, wc = (w & 1) * 64;
    const int fr = l & 15;
    const int ko = (((l >> 4) ^ ((fr >> 1) & 3))) * 8;   // swizzled read unit

    STAGE(0, 0);
    STAGE(1, 32);

    for (int t = 0; t < 32; ++t) {
        if (t < 31) asm volatile("s_waitcnt vmcnt(4)" ::: "memory");
        else        asm volatile("s_waitcnt vmcnt(0)" ::: "memory");
        __builtin_amdgcn_sched_barrier(0);
        __builtin_amdgcn_s_barrier();       // raw barrier: no vmcnt(0) drain
        __builtin_amdgcn_sched_barrier(0);

        if (t < 30) STAGE((t + 2) % 3, (t + 2) * 32);

        const int cur = t % 3;
        short8 av[4], bv[4];
        #pragma unroll
        for (int m = 0; m < 4; ++m)
            av[m] = *reinterpret_cast<const short8*>(&LDS[cur][0][(wr + m * 16 + fr) * 32 + ko]);
        #pragma unroll
        for (int n = 0; n < 4; ++n)
            bv[n] = *reinterpret_cast<const short8*>(&LDS[cur][1][(wc + n * 16 + fr) * 32 + ko]);
        __builtin_amdgcn_s_setprio(1);
        #pragma unroll
        for (int m = 0; m < 4; ++m)
            #pragma unroll
            for (int n = 0; n < 4; ++n)
                acc[m][n] = MFMA16(av[m], bv[n], acc[m][n]);
        __builtin_amdgcn_s_setprio(0);
    }

    #pragma unroll
    for (int n = 0; n < 4; ++n) {
        const int c = bcol + wc + n * 16 + fr;
        const float bi = bias[c];
        #pragma unroll
        for (int m = 0; m < 4; ++m) {
            #pragma unroll
            for (int j = 0; j < 4; ++j) {
                const int r = brow + wr + m * 16 + (l >> 4) * 4 + j;
                float v = (acc[m][n][j] + bi) * scale;
                const int rn = r >> 2, b = r & 3, hh = c >> 6, dd = c & 63;
                if (epi == 1) {
                    out[((size_t)(b * H_ + hh) * 1024 + rn) * 64 + dd] = f2bf(v);
                } else {
                    if (dwm) v *= dwm[(size_t)r * H_ + hh];
                    out[(((size_t)(b * H_ + hh) * 32 + (rn >> 5)) * 64 + dd) * 32 + (rn & 31)] = f2bf(v);
                }
            }
        }
    }
}

// ---------------------------------------------------------------------------
// Output projection, 2-term (R13): out = ohi . (whi + wlo)^T + b.
// ---------------------------------------------------------------------------
__global__ __launch_bounds__(256) void outproj_mfma(
    const unsigned short* __restrict__ ahi,
    const unsigned short* __restrict__ whi,
    const unsigned short* __restrict__ wlo,
    const float* __restrict__ out_b,
    float* __restrict__ out)
{
    __shared__ unsigned short LDS[2][3][128 * 32];   // 48 KB

    const int tid = threadIdx.x;
    const int l = tid & 63, w = tid >> 6;
    const int brow = blockIdx.y * 128;
    const int bcol = blockIdx.x * 128;

    const int ch0 = w * 64 + l;
    const int ch1 = 256 + w * 64 + l;
    const int u0 = ((ch0 & 3) ^ ((ch0 >> 3) & 3)) * 8;
    const int u1 = ((ch1 & 3) ^ ((ch1 >> 3) & 3)) * 8;
    const size_t ra0 = (size_t)(brow + (ch0 >> 2)) * E_ + u0;
    const size_t ra1 = (size_t)(brow + (ch1 >> 2)) * E_ + u1;
    const size_t rb0 = (size_t)(bcol + (ch0 >> 2)) * E_ + u0;
    const size_t rb1 = (size_t)(bcol + (ch1 >> 2)) * E_ + u1;

    auto STAGE = [&](int buf, int kt) {
        gload16(ahi + ra0 + kt, &LDS[buf][0][(size_t)w * 512]);
        gload16(ahi + ra1 + kt, &LDS[buf][0][(size_t)(4 + w) * 512]);
        gload16(whi + rb0 + kt, &LDS[buf][1][(size_t)w * 512]);
        gload16(whi + rb1 + kt, &LDS[buf][1][(size_t)(4 + w) * 512]);
        gload16(wlo + rb0 + kt, &LDS[buf][2][(size_t)w * 512]);
        gload16(wlo + rb1 + kt, &LDS[buf][2][(size_t)(4 + w) * 512]);
    };

    f32x4 acc[4][4];
    #pragma unroll
    for (int m = 0; m < 4; ++m)
        #pragma unroll
        for (int n = 0; n < 4; ++n)
            acc[m][n] = (f32x4){0.f, 0.f, 0.f, 0.f};

    const int wr = (w >> 1) * 64, wc = (w & 1) * 64;
    const int fr = l & 15;
    const int ko = (((l >> 4) ^ ((fr >> 1) & 3))) * 8;   // swizzled read unit

    STAGE(0, 0);
    __syncthreads();
    for (int t = 0; t < 32; ++t) {
        const int cur = t & 1;
        if (t < 31) STAGE(cur ^ 1, (t + 1) * 32);
        short8 ah[4], bh[4], bl[4];
        #pragma unroll
        for (int m = 0; m < 4; ++m)
            ah[m] = *reinterpret_cast<const short8*>(&LDS[cur][0][(wr + m * 16 + fr) * 32 + ko]);
        #pragma unroll
        for (int n = 0; n < 4; ++n) {
            bh[n] = *reinterpret_cast<const short8*>(&LDS[cur][1][(wc + n * 16 + fr) * 32 + ko]);
            bl[n] = *reinterpret_cast<const short8*>(&LDS[cur][2][(wc + n * 16 + fr) * 32 + ko]);
        }
        __builtin_amdgcn_s_setprio(1);
        #pragma unroll
        for (int m = 0; m < 4; ++m)
            #pragma unroll
            for (int n = 0; n < 4; ++n) {
                acc[m][n] = MFMA16(ah[m], bh[n], acc[m][n]);
                acc[m][n] = MFMA16(ah[m], bl[n], acc[m][n]);
            }
        __builtin_amdgcn_s_setprio(0);
        if (t < 31) __syncthreads();
    }

    #pragma unroll
    for (int n = 0; n < 4; ++n) {
        const int c = bcol + wc + n * 16 + fr;
        const float bi = out_b[c];
        #pragma unroll
        for (int m = 0; m < 4; ++m)
            #pragma unroll
            for (int j = 0; j < 4; ++j) {
                const int r = brow + wr + m * 16 + (l >> 4) * 4 + j;
                out[(size_t)r * E_ + c] = acc[m][n][j] + bi;
            }
    }
}

// ---------------------------------------------------------------------------
// MFMA flash attention, full-S (R15 structure, unchanged).
// ---------------------------------------------------------------------------
__global__ __launch_bounds__(256) void attn_mfma(
    const unsigned short* __restrict__ qbf,
    const unsigned short* __restrict__ kbf,
    const unsigned short* __restrict__ nkbf,
    const unsigned short* __restrict__ vtb,
    const unsigned short* __restrict__ nvtb,
    const unsigned char* __restrict__ kpm,
    const unsigned char* __restrict__ npm,
    unsigned short* __restrict__ ohi)
{
    __shared__ unsigned short Kl[2][64 * 64];   // 8 KB each, swizzled rows
    __shared__ unsigned short Vl[2][64 * 64];   // 8 KB each, [kg][d][k8]
    __shared__ unsigned short maskB[2048];      // bf16 additive mask (4 KB)
    __shared__ int tmask[32];

    const int tid = threadIdx.x;
    const int l = tid & 63, w = tid >> 6;
    const int bh = blockIdx.x, b = bh >> 4, h = bh & 15;
    const int t0 = blockIdx.y * 64;

    if (tid < 32) tmask[tid] = 0;
    __syncthreads();
    {
        const unsigned short negbf = f2bf(-60000.f);
        for (int s = tid; s < 2048; s += 256) {
            int masked;
            if (s < N_) masked = kpm[(size_t)b * N_ + s] ? 1 : 0;
            else {
                const int m = s - N_;
                masked = (m < M_ && !npm[(size_t)b * M_ + m]) ? 0 : 1;
            }
            maskB[s] = masked ? negbf : (unsigned short)0;
            if (masked) atomicOr(&tmask[s >> 6], 1);
        }
    }

    auto STAGE = [&](int buf, int s0) {
        const unsigned short* ksrc;
        const unsigned short* vsrc;
        int srow;
        if (s0 < N_) { ksrc = kbf;  vsrc = vtb;  srow = s0; }
        else         { ksrc = nkbf; vsrc = nvtb; srow = s0 - N_; }
        #pragma unroll
        for (int u = 0; u < 2; ++u) {
            const int c = u * 256 + tid;
            const int krow = c >> 3;
            const int kcol = ((c & 7) * 16) ^ ((krow & 7) << 4);
            gload16((const unsigned char*)ksrc +
                        ((size_t)(bh * 1024 + srow + krow) * 64) * 2 + kcol,
                    (unsigned char*)&Kl[buf][0] + c * 16);
            const int kg = c >> 6;
            const int dd = c & 63;
            const int kv = srow + kg * 8;
            const int kp = kv >> 5;
            gload16((const unsigned char*)vsrc +
                        (((size_t)(bh * 32 + kp) * 64 + dd) * 32 + (kv & 31)) * 2,
                    (unsigned char*)&Vl[buf][0] + c * 16);
        }
    };

    const int g = l >> 4;
    const int q = l & 15;

    const int qrow = t0 + w * 16 + q;
    const short8 aq0 = *reinterpret_cast<const short8*>(&qbf[((size_t)bh * T_ + qrow) * 64 + g * 8]);
    const short8 aq1 = *reinterpret_cast<const short8*>(&qbf[((size_t)bh * T_ + qrow) * 64 + 32 + g * 8]);

    float mold = -30000.f, lrp = 0.f;   // lrp: per-lane PARTIAL row-sum
    f32x4 acco[4];
    #pragma unroll
    for (int n = 0; n < 4; ++n) acco[n] = (f32x4){0.f, 0.f, 0.f, 0.f};

    const int ksw = (l & 7) << 4;
    const int kb0 = q * 128 + ((g * 16) ^ ksw);        // + n*2048
    const int kb1 = q * 128 + ((64 + g * 16) ^ ksw);   // + n*2048
    const int vb0 = g * 1024 + q * 16;                 // + n*256 (+4096 half 1)

    const int src0 = (g & 1) * 32 + q;   // words 0,1
    const int src1 = src0 + 16;          // words 2,3
    const bool selhi = (l & 32) != 0;

    STAGE(0, 0);
    __syncthreads();

    for (int it = 0; it < 32; ++it) {
        const int s0 = it * 64;
        const int cur = it & 1;
        if (it < 31) STAGE(cur ^ 1, s0 + 64);

        const unsigned char* const Kc = (const unsigned char*)&Kl[cur][0];
        const unsigned char* const Vc = (const unsigned char*)&Vl[cur][0];

        f32x4 accs[4];
        #pragma unroll
        for (int n = 0; n < 4; ++n) accs[n] = (f32x4){0.f, 0.f, 0.f, 0.f};
        __builtin_amdgcn_s_setprio(1);
        #pragma unroll
        for (int n = 0; n < 4; ++n) {
            const short8 k0 = *reinterpret_cast<const short8*>(Kc + n * 2048 + kb0);
            const short8 k1 = *reinterpret_cast<const short8*>(Kc + n * 2048 + kb1);
            accs[n] = MFMA16(k0, aq0, accs[n]);
            accs[n] = MFMA16(k1, aq1, accs[n]);
        }
        __builtin_amdgcn_s_setprio(0);

        if (tmask[s0 >> 6]) {
            #pragma unroll
            for (int n = 0; n < 4; ++n) {
                const ushort4 mz = *reinterpret_cast<const ushort4*>(&maskB[s0 + n * 16 + g * 4]);
                accs[n][0] += bf2f(mz.x);
                accs[n][1] += bf2f(mz.y);
                accs[n][2] += bf2f(mz.z);
                accs[n][3] += bf2f(mz.w);
            }
        }

        float mx;
        {
            const float t0_ = fmaxf(fmaxf(accs[0][0], accs[0][1]), accs[0][2]);
            const float t1_ = fmaxf(fmaxf(accs[0][3], accs[1][0]), accs[1][1]);
            const float t2_ = fmaxf(fmaxf(accs[1][2], accs[1][3]), accs[2][0]);
            const float t3_ = fmaxf(fmaxf(accs[2][1], accs[2][2]), accs[2][3]);
            const float t4_ = fmaxf(fmaxf(accs[3][0], accs[3][1]), accs[3][2]);
            const float t5_ = fmaxf(fmaxf(t0_, t1_), t2_);
            const float t6_ = fmaxf(fmaxf(t3_, t4_), accs[3][3]);
            mx = fmaxf(t5_, t6_);
        }
        mx = fmaxf(mx, __shfl_xor(mx, 16));
        mx = fmaxf(mx, __shfl_xor(mx, 32));

        if (__any(mx > mold + 8.f)) {
            const float mn = fmaxf(mold, mx);
            const float f = __builtin_amdgcn_exp2f(mold - mn);
            mold = mn;
            lrp *= f;
            #pragma unroll
            for (int n = 0; n < 4; ++n)
                #pragma unroll
                for (int j = 0; j < 4; ++j) acco[n][j] *= f;
        }

        float p[4][4];
        float ps = 0.f;
        #pragma unroll
        for (int n = 0; n < 4; ++n)
            #pragma unroll
            for (int j = 0; j < 4; ++j) {
                p[n][j] = __builtin_amdgcn_exp2f(accs[n][j] - mold);
                ps += p[n][j];
            }
        lrp += ps;

        unsigned int ppk[4][2];
        #pragma unroll
        for (int n = 0; n < 4; ++n) {
            ppk[n][0] = cvt_pk_bf16(p[n][0], p[n][1]);
            ppk[n][1] = cvt_pk_bf16(p[n][2], p[n][3]);
        }

        union UF { int4 i4; short8 s8; } pf[2];
        #pragma unroll
        for (int hh2 = 0; hh2 < 2; ++hh2) {
            const unsigned int a0 = __shfl((int)ppk[2 * hh2][0],     src0);
            const unsigned int b0 = __shfl((int)ppk[2 * hh2 + 1][0], src0);
            const unsigned int a1 = __shfl((int)ppk[2 * hh2][1],     src0);
            const unsigned int b1 = __shfl((int)ppk[2 * hh2 + 1][1], src0);
            const unsigned int a2 = __shfl((int)ppk[2 * hh2][0],     src1);
            const unsigned int b2 = __shfl((int)ppk[2 * hh2 + 1][0], src1);
            const unsigned int a3 = __shfl((int)ppk[2 * hh2][1],     src1);
            const unsigned int b3 = __shfl((int)ppk[2 * hh2 + 1][1], src1);
            pf[hh2].i4.x = selhi ? b0 : a0;
            pf[hh2].i4.y = selhi ? b1 : a1;
            pf[hh2].i4.z = selhi ? b2 : a2;
            pf[hh2].i4.w = selhi ? b3 : a3;
        }

        __builtin_amdgcn_s_setprio(1);
        #pragma unroll
        for (int n = 0; n < 4; ++n) {
            const short8 v0 = *reinterpret_cast<const short8*>(Vc + n * 256 + vb0);
            const short8 v1 = *reinterpret_cast<const short8*>(Vc + 4096 + n * 256 + vb0);
            acco[n] = MFMA16(v0, pf[0].s8, acco[n]);
            acco[n] = MFMA16(v1, pf[1].s8, acco[n]);
        }
        __builtin_amdgcn_s_setprio(0);

        __syncthreads();
    }

    float lr = lrp;
    lr += __shfl_xor(lr, 16);
    lr += __shfl_xor(lr, 32);
    const float linv = 1.f / lr;
    const int t = t0 + w * 16 + q;
    const size_t obase = ((size_t)t * B_ + b) * E_ + h * 64;
    #pragma unroll
    for (int n = 0; n < 4; ++n) {
        ushort4 h4;
        h4.x = f2bf(acco[n][0] * linv);
        h4.y = f2bf(acco[n][1] * linv);
        h4.z = f2bf(acco[n][2] * linv);
        h4.w = f2bf(acco[n][3] * linv);
        *reinterpret_cast<ushort4*>(&ohi[obase + n * 16 + g * 4]) = h4;
    }
}

// ---------------------------------------------------------------------------
extern "C" void kernel_launch(void* const* d_in, const int* in_sizes, int n_in,
                              void* d_out, int out_size, void* d_ws, size_t ws_size,
                              hipStream_t stream) {
    const float* query    = (const float*)d_in[0];
    const float* key      = (const float*)d_in[1];
    const float* node_key = (const float*)d_in[2];
    const float* ipw      = (const float*)d_in[3];
    const float* ipb      = (const float*)d_in[4];
    const float* out_w    = (const float*)d_in[5];
    const float* out_b    = (const float*)d_in[6];
    const float* dw_w     = (const float*)d_in[7];
    const float* dw_b     = (const float*)d_in[8];
    const unsigned char* kpm = (const unsigned char*)d_in[9];
    const unsigned char* npm = (const unsigned char*)d_in[10];
    float* out = (float*)d_out;

    char* p = (char*)d_ws;
    auto alloc = [&](size_t bytes) {
        char* r = p;
        p += (bytes + 255) & ~(size_t)255;
        return r;
    };
    unsigned short* xq    = (unsigned short*)alloc((size_t)4096 * 1024 * 2);
    unsigned short* xk    = (unsigned short*)alloc((size_t)4096 * 1024 * 2);
    unsigned short* xn    = (unsigned short*)alloc((size_t)4096 * 1024 * 2);
    unsigned short* wbf   = (unsigned short*)alloc((size_t)3072 * 1024 * 2);
    unsigned short* wohi  = (unsigned short*)alloc((size_t)1024 * 1024 * 2);
    unsigned short* wolo  = (unsigned short*)alloc((size_t)1024 * 1024 * 2);
    unsigned short* qb    = (unsigned short*)alloc((size_t)64 * 1024 * 64 * 2);
    unsigned short* kb_   = (unsigned short*)alloc((size_t)64 * 1024 * 64 * 2);
    unsigned short* nkb   = (unsigned short*)alloc((size_t)64 * 1024 * 64 * 2);
    unsigned short* vtb   = (unsigned short*)alloc((size_t)64 * 1024 * 64 * 2);
    unsigned short* nvtb  = (unsigned short*)alloc((size_t)64 * 1024 * 64 * 2);
    unsigned short* ohi   = (unsigned short*)alloc((size_t)4096 * 1024 * 2);
    float*          dwb   = (float*)alloc((size_t)4096 * 16 * 4);

    const dim3 blk(256);

    // 1) all conversions + dw gate in one dispatch
    conv_all<<<dim3(16384 + 4092), blk, 0, stream>>>(
        query, key, node_key, ipw, out_w, dw_w, dw_b,
        xq, xk, xn, wbf, wohi, wolo, dwb);

    // 2) fused input projections (128x128, counted-vmcnt + T2 swizzle)
    proj_mfma<<<dim3(8, 32, 5), blk, 0, stream>>>(xq, xk, xn, wbf, ipb, dwb,
                                                  qb, kb_, vtb, nkb, nvtb);

    // 3) attention, full-S -> ohi (bf16)
    attn_mfma<<<dim3(64, 16), blk, 0, stream>>>(qb, kb_, nkb, vtb, nvtb,
                                                kpm, npm, ohi);

    // 4) output projection (2-term: ohi.(whi+wlo)) -> d_out fp32
    outproj_mfma<<<dim3(8, 32), blk, 0, stream>>>(ohi, wohi, wolo, out_b, out);
}